// Round 1
// baseline (9661.707 us; speedup 1.0000x reference)
//
#include <hip/hip_runtime.h>

#define TS 20
#define TS2 400   // 20*20

// Computes one _sym layer: y[:, CO_OFF:CO_OFF+COUT] =
//   relu(conv4d(x, w) + b) + relu(conv4d(x, w_perm) + b)
// where w has kernel shape (KAO,KAO,KAI,KAI) and w_perm[a,b,c,d] = w[c,d,a,b].
// x: [N][CIN][20][20][20][20], y: [N][COUT_TOTAL][20][20][20][20]
// Block = one (n, o1, o2); 448 threads, threads 0..399 map to (h2,w2).
template<int CIN, int COUT, int KAO, int KAI, int COUT_TOTAL, int CO_OFF>
__global__ __launch_bounds__(448)
void conv4d_sym(const float* __restrict__ x, const float* __restrict__ w,
                const float* __restrict__ bias, float* __restrict__ y)
{
    static_assert(KAI == 5, "inner kernel of variant A must be 5");
    static_assert(KAO <= 5, "patch radius assumes kernels <= 5");
    constexpr int PA_O = KAO / 2, PA_I = KAI / 2;   // variant A pads (outer, inner)
    constexpr int PB_O = KAI / 2, PB_I = KAO / 2;   // variant B pads (outer, inner)
    constexpr int R = 2;                            // union outer radius (always 2)
    constexpr int WCI = KAO * KAO * KAI * KAI;      // weight stride per ci
    constexpr int WCO = CIN * WCI;                  // weight stride per co

    const int bid = blockIdx.x;
    const int o2 = bid % TS;
    const int o1 = (bid / TS) % TS;
    const int n  = bid / (TS * TS);
    const int tid = (int)threadIdx.x;
    const int h2 = tid / TS, w2 = tid % TS;
    const bool active = tid < TS2;

    // two 24x24 plane buffers with permanent zero borders (SAME padding)
    __shared__ float lds[2][24][24];
    for (int i = tid; i < 2 * 24 * 24; i += 448) ((float*)lds)[i] = 0.0f;
    __syncthreads();

    float accA[COUT], accB[COUT];
#pragma unroll
    for (int c = 0; c < COUT; ++c) { accA[c] = 0.0f; accB[c] = 0.0f; }

    int buf = 0;
    for (int ci = 0; ci < CIN; ++ci) {
        const float* xci = x + (((size_t)n * CIN + ci) * TS2) * TS2;
        for (int d1 = -R; d1 <= R; ++d1) {
            const int i1 = o1 + d1;
            if (i1 < 0 || i1 >= TS) continue;       // block-uniform: no divergence
            for (int d2 = -R; d2 <= R; ++d2) {
                const int i2 = o2 + d2;
                if (i2 < 0 || i2 >= TS) continue;

                // stage inner plane x[n,ci,i1,i2,:,:] into LDS interior
                const float* plane = xci + (size_t)(i1 * TS + i2) * TS2;
                if (active) lds[buf][2 + h2][2 + w2] = plane[tid];
                __syncthreads();
                // NOTE: single barrier per plane is safe with double buffering:
                // stage(i+2) into this buffer happens after sync(i+1), which
                // happens after every thread's compute(i).

                // pull 5x5 patch (radius 2 around (h2,w2)) into registers
                float p[5][5];
#pragma unroll
                for (int a = 0; a < 5; ++a)
#pragma unroll
                    for (int bb = 0; bb < 5; ++bb)
                        p[a][bb] = lds[buf][h2 + a][w2 + bb];

                // ---- variant A: outer kernel KAOxKAO, inner KAIxKAI ----
                if (d1 >= -PA_O && d1 <= PA_O && d2 >= -PA_O && d2 <= PA_O) {
                    const int kA1 = d1 + PA_O, kA2 = d2 + PA_O;
                    const float* wa = w + ci * WCI + (kA1 * KAO + kA2) * (KAI * KAI);
#pragma unroll
                    for (int co = 0; co < COUT; ++co) {
                        const float* wc = wa + co * WCO;
                        float s = 0.0f;
#pragma unroll
                        for (int t3 = 0; t3 < KAI; ++t3)
#pragma unroll
                            for (int t4 = 0; t4 < KAI; ++t4)
                                s += p[t3 + 2 - PA_I][t4 + 2 - PA_I] * wc[t3 * KAI + t4];
                        accA[co] += s;
                    }
                }

                // ---- variant B (permuted): outer KAIxKAI, inner KAOxKAO ----
                if (d1 >= -PB_O && d1 <= PB_O && d2 >= -PB_O && d2 <= PB_O) {
                    const int kB1 = d1 + PB_O, kB2 = d2 + PB_O;
                    const float* wb = w + ci * WCI + kB1 * KAI + kB2;
#pragma unroll
                    for (int co = 0; co < COUT; ++co) {
                        const float* wc = wb + co * WCO;
                        float s = 0.0f;
#pragma unroll
                        for (int t3 = 0; t3 < KAO; ++t3)
#pragma unroll
                            for (int t4 = 0; t4 < KAO; ++t4)
                                s += p[t3 + 2 - PB_I][t4 + 2 - PB_I]
                                     * wc[(t3 * KAO + t4) * (KAI * KAI)];
                        accB[co] += s;
                    }
                }

                buf ^= 1;
            }
        }
    }

    if (active) {
        const size_t obase = (size_t)n * COUT_TOTAL + CO_OFF;
        const size_t sp = (size_t)(o1 * TS + o2) * TS2 + tid;
#pragma unroll
        for (int co = 0; co < COUT; ++co) {
            float bsc = bias[co];
            float va = accA[co] + bsc; va = va > 0.0f ? va : 0.0f;
            float vb = accB[co] + bsc; vb = vb > 0.0f ? vb : 0.0f;
            y[(obase + co) * (size_t)TS2 * TS2 + sp] = va + vb;
        }
    }
}

extern "C" void kernel_launch(void* const* d_in, const int* in_sizes, int n_in,
                              void* d_out, int out_size, void* d_ws, size_t ws_size,
                              hipStream_t stream)
{
    const float* x   = (const float*)d_in[0];
    const float* w0  = (const float*)d_in[1];
    const float* b0  = (const float*)d_in[2];
    const float* w10 = (const float*)d_in[3];
    const float* b10 = (const float*)d_in[4];
    const float* w11 = (const float*)d_in[5];
    const float* b11 = (const float*)d_in[6];
    const float* w2  = (const float*)d_in[7];
    const float* b2  = (const float*)d_in[8];
    float* out = (float*)d_out;

    // workspace: y1 [4][16][20^4], y2 [4][16][20^4]  (40.96 MB each)
    float* y1 = (float*)d_ws;
    float* y2 = y1 + (size_t)4 * 16 * TS2 * TS2;

    dim3 grid(4 * TS * TS), block(448);
    // layer 0: x [4,1,...] -> y1 [4,16,...]
    conv4d_sym<1, 16, 5, 5, 16, 0><<<grid, block, 0, stream>>>(x, w0, b0, y1);
    // layer 10: y1 -> y2[:, 0:8]   (kernel (3,3,5,5))
    conv4d_sym<16, 8, 3, 5, 16, 0><<<grid, block, 0, stream>>>(y1, w10, b10, y2);
    // layer 11: y1 -> y2[:, 8:16]  (kernel (5,5,5,5))
    conv4d_sym<16, 8, 5, 5, 16, 8><<<grid, block, 0, stream>>>(y1, w11, b11, y2);
    // layer 2: y2 -> out [4,1,...]
    conv4d_sym<16, 1, 5, 5, 1, 0><<<grid, block, 0, stream>>>(y2, w2, b2, out);
}

// Round 2
// 1906.869 us; speedup vs baseline: 5.0668x; 5.0668x over previous
//
#include <hip/hip_runtime.h>

#define TS 20
#define TS2 400   // 20*20

typedef __attribute__((ext_vector_type(8))) __bf16 bf16x8;
typedef __attribute__((ext_vector_type(4))) float  f32x4;
typedef __attribute__((ext_vector_type(4))) int    int4v;

// ---------------------------------------------------------------------------
// fp32 direct-conv _sym layer (used for layer 0 and layer 2).
// ILV=true: write output as bf16, layout [n][o1][o2][h2][w2][ci] (ci innermost)
// ILV=false: write fp32 planar [n][ch][o1][o2][h2][w2]
// ---------------------------------------------------------------------------
template<int CIN, int COUT, int KAO, int KAI, int COUT_TOTAL, int CO_OFF, bool ILV>
__global__ __launch_bounds__(448)
void conv4d_sym(const float* __restrict__ x, const float* __restrict__ w,
                const float* __restrict__ bias, void* __restrict__ y)
{
    static_assert(KAI == 5, "inner kernel of variant A must be 5");
    constexpr int PA_O = KAO / 2, PA_I = KAI / 2;
    constexpr int PB_O = KAI / 2, PB_I = KAO / 2;
    constexpr int R = 2;
    constexpr int WCI = KAO * KAO * KAI * KAI;
    constexpr int WCO = CIN * WCI;

    const int bid = blockIdx.x;
    const int o2 = bid % TS;
    const int o1 = (bid / TS) % TS;
    const int n  = bid / (TS * TS);
    const int tid = (int)threadIdx.x;
    const int h2 = tid / TS, w2 = tid % TS;
    const bool active = tid < TS2;

    __shared__ float lds[2][24][24];
    for (int i = tid; i < 2 * 24 * 24; i += 448) ((float*)lds)[i] = 0.0f;
    __syncthreads();

    float accA[COUT], accB[COUT];
#pragma unroll
    for (int c = 0; c < COUT; ++c) { accA[c] = 0.0f; accB[c] = 0.0f; }

    int buf = 0;
    for (int ci = 0; ci < CIN; ++ci) {
        const float* xci = x + (((size_t)n * CIN + ci) * TS2) * TS2;
        for (int d1 = -R; d1 <= R; ++d1) {
            const int i1 = o1 + d1;
            if (i1 < 0 || i1 >= TS) continue;
            for (int d2 = -R; d2 <= R; ++d2) {
                const int i2 = o2 + d2;
                if (i2 < 0 || i2 >= TS) continue;

                const float* plane = xci + (size_t)(i1 * TS + i2) * TS2;
                if (active) lds[buf][2 + h2][2 + w2] = plane[tid];
                __syncthreads();

                if (active) {
                    float p[5][5];
#pragma unroll
                    for (int a = 0; a < 5; ++a)
#pragma unroll
                        for (int bb = 0; bb < 5; ++bb)
                            p[a][bb] = lds[buf][h2 + a][w2 + bb];

                    if (d1 >= -PA_O && d1 <= PA_O && d2 >= -PA_O && d2 <= PA_O) {
                        const int kA1 = d1 + PA_O, kA2 = d2 + PA_O;
                        const float* wa = w + ci * WCI + (kA1 * KAO + kA2) * (KAI * KAI);
#pragma unroll
                        for (int co = 0; co < COUT; ++co) {
                            const float* wc = wa + co * WCO;
                            float s = 0.0f;
#pragma unroll
                            for (int t3 = 0; t3 < KAI; ++t3)
#pragma unroll
                                for (int t4 = 0; t4 < KAI; ++t4)
                                    s += p[t3 + 2 - PA_I][t4 + 2 - PA_I] * wc[t3 * KAI + t4];
                            accA[co] += s;
                        }
                    }
                    if (d1 >= -PB_O && d1 <= PB_O && d2 >= -PB_O && d2 <= PB_O) {
                        const int kB1 = d1 + PB_O, kB2 = d2 + PB_O;
                        const float* wb = w + ci * WCI + kB1 * KAI + kB2;
#pragma unroll
                        for (int co = 0; co < COUT; ++co) {
                            const float* wc = wb + co * WCO;
                            float s = 0.0f;
#pragma unroll
                            for (int t3 = 0; t3 < KAO; ++t3)
#pragma unroll
                                for (int t4 = 0; t4 < KAO; ++t4)
                                    s += p[t3 + 2 - PB_I][t4 + 2 - PB_I]
                                         * wc[(t3 * KAO + t4) * (KAI * KAI)];
                            accB[co] += s;
                        }
                    }
                }
                buf ^= 1;
            }
        }
    }

    if (active) {
        if constexpr (ILV) {
            __bf16* yb = (__bf16*)y;
            const size_t base = ((size_t)((n * TS + o1) * TS + o2) * TS2 + tid) * 16;
#pragma unroll
            for (int co = 0; co < COUT; ++co) {
                float bsc = bias[co];
                float va = accA[co] + bsc; va = va > 0.0f ? va : 0.0f;
                float vb = accB[co] + bsc; vb = vb > 0.0f ? vb : 0.0f;
                yb[base + co] = (__bf16)(va + vb);
            }
        } else {
            float* yf = (float*)y;
            const size_t obase = (size_t)n * COUT_TOTAL + CO_OFF;
            const size_t sp = (size_t)(o1 * TS + o2) * TS2 + tid;
#pragma unroll
            for (int co = 0; co < COUT; ++co) {
                float bsc = bias[co];
                float va = accA[co] + bsc; va = va > 0.0f ? va : 0.0f;
                float vb = accB[co] + bsc; vb = vb > 0.0f ? vb : 0.0f;
                yf[(obase + co) * (size_t)TS2 * TS2 + sp] = va + vb;
            }
        }
    }
}

// ---------------------------------------------------------------------------
// Weight pack for the fused middle layers.
// wpk[off][m][ci] bf16, off = outer(25)*26 + inner(0..25), inner 25 = zero pad.
// m: 0-7 L10-A co, 8-15 L10-B co, 16-23 L11-A co, 24-31 L11-B co.
// ---------------------------------------------------------------------------
__global__ __launch_bounds__(256)
void pack_weights(const float* __restrict__ w10, const float* __restrict__ w11,
                  __bf16* __restrict__ wpk)
{
    int idx = blockIdx.x * 256 + (int)threadIdx.x;
    if (idx >= 650 * 512) return;
    const int ci  = idx & 15;
    const int m   = (idx >> 4) & 31;
    const int off = idx >> 9;
    const int inner = off % 26, outer = off / 26;
    const int d1 = outer / 5 - 2, d2 = outer % 5 - 2;
    float v = 0.0f;
    if (inner < 25) {
        const int d3 = inner / 5 - 2, d4 = inner % 5 - 2;
        const int co = m & 7;
        const bool isB  = (m & 8)  != 0;
        const bool is11 = (m & 16) != 0;
        if (is11) {
            int k1, k2, k3, k4;
            if (!isB) { k1 = d1 + 2; k2 = d2 + 2; k3 = d3 + 2; k4 = d4 + 2; }
            else      { k1 = d3 + 2; k2 = d4 + 2; k3 = d1 + 2; k4 = d2 + 2; }
            v = w11[((((co * 16 + ci) * 5 + k1) * 5 + k2) * 5 + k3) * 5 + k4];
        } else {
            if (!isB) {
                if (d1 >= -1 && d1 <= 1 && d2 >= -1 && d2 <= 1)
                    v = w10[((((co * 16 + ci) * 3 + (d1 + 1)) * 3 + (d2 + 1)) * 5 + (d3 + 2)) * 5 + (d4 + 2)];
            } else {
                if (d3 >= -1 && d3 <= 1 && d4 >= -1 && d4 <= 1)
                    v = w10[((((co * 16 + ci) * 3 + (d3 + 1)) * 3 + (d4 + 1)) * 5 + (d1 + 2)) * 5 + (d2 + 2)];
            }
        }
    }
    wpk[idx] = (__bf16)v;
}

// ---------------------------------------------------------------------------
// Fused layers 10+11 via MFMA 16x16x32 bf16 implicit GEMM.
// Block = (n, o1, o2): 32 output channels x 400 spatial. 5 waves x 5 N-tiles.
// K = 650 offsets x 16 ci; per K-chunk: 2 offsets x 16 ci = 32.
// y1: bf16 [n][o1][o2][h2][w2][ci];  y2: fp32 planar [n][16][o1][o2][h2][w2]
// ---------------------------------------------------------------------------
__global__ __launch_bounds__(320)
void conv4d_mid_mfma(const __bf16* __restrict__ y1, const __bf16* __restrict__ wpk,
                     const float* __restrict__ b10, const float* __restrict__ b11,
                     float* __restrict__ y2)
{
    __shared__ __bf16 lds[2][9216];   // [24][24][16ci], zero borders

    const int tid  = (int)threadIdx.x;
    const int lane = tid & 63;
    const int wave = tid >> 6;
    const int bid = blockIdx.x;
    const int o2 = bid % TS;
    const int o1 = (bid / TS) % TS;
    const int n  = bid / (TS * TS);

    // zero both LDS buffers once (borders persist; interior overwritten per plane)
    for (int i = tid; i < 9216; i += 320) ((int*)lds)[i] = 0;

    const int mrow = lane & 15;       // A-row within M-tile == D column (spatial)
    const int sub  = lane >> 4;       // 0..3 k-block
    const int ci0  = (sub & 1) * 8;
    // A-fragment lane offset within a 2-offset chunk (shorts): (off_sel)*512 + m*16 + ci0
    const int aoff = (sub >> 1) * 512 + mrow * 16 + ci0;

    int sbase[5];
#pragma unroll
    for (int i = 0; i < 5; ++i) {
        const int p  = (wave * 5 + i) * 16 + mrow;
        const int h2 = p / TS, w2 = p % TS;
        sbase[i] = ((h2 + 2) * 24 + (w2 + 2)) * 16 + ci0;
    }

    f32x4 acc[5][2];
#pragma unroll
    for (int i = 0; i < 5; ++i) {
        acc[i][0] = (f32x4){0.f, 0.f, 0.f, 0.f};
        acc[i][1] = (f32x4){0.f, 0.f, 0.f, 0.f};
    }

    __syncthreads();   // LDS zeroing complete

    int buf = 0;
    for (int d1 = -2; d1 <= 2; ++d1) {
        const int i1 = o1 + d1;
        if (i1 < 0 || i1 >= TS) continue;
        for (int d2 = -2; d2 <= 2; ++d2) {
            const int i2 = o2 + d2;
            if (i2 < 0 || i2 >= TS) continue;

            // ---- stage plane (i1,i2): 20x20x16ci bf16 = 800 x 16B ----
            const __bf16* src = y1 + (size_t)((n * TS + i1) * TS + i2) * TS2 * 16;
            for (int c = tid; c < 800; c += 320) {
                const int h = c / 40, rem = c % 40;
                int4v v = *(const int4v*)(src + c * 8);
                *(int4v*)(&lds[buf][((h + 2) * 24 + 2) * 16 + rem * 8]) = v;
            }
            __syncthreads();
            // (single barrier per plane is safe with double buffering: staging
            //  into buf^1 never races compute on buf; re-staging buf waits for
            //  the next barrier which follows all compute on buf)

            // ---- compute: 13 K-chunks of (2 offsets x 16 ci) ----
            const int outer = (d1 + 2) * 5 + (d2 + 2);
            const __bf16* wbase = wpk + (size_t)outer * 26 * 512;

            // per-lane inner offset for chunk ic: e = 2*ic + (sub>>1)
            bf16x8 a0 = *(const bf16x8*)(wbase + aoff);
            bf16x8 a1 = *(const bf16x8*)(wbase + aoff + 256);
            for (int ic = 0; ic < 13; ++ic) {
                bf16x8 na0, na1;
                if (ic < 12) {
                    na0 = *(const bf16x8*)(wbase + (ic + 1) * 1024 + aoff);
                    na1 = *(const bf16x8*)(wbase + (ic + 1) * 1024 + aoff + 256);
                }
                const int e = 2 * ic + (sub >> 1);
                int d3 = 0, d4 = 0;
                if (e < 25) { d3 = e / 5 - 2; d4 = e % 5 - 2; }
                const int delta = (d3 * 24 + d4) * 16;
#pragma unroll
                for (int i = 0; i < 5; ++i) {
                    bf16x8 bfr = *(const bf16x8*)(&lds[buf][sbase[i] + delta]);
                    acc[i][0] = __builtin_amdgcn_mfma_f32_16x16x32_bf16(a0, bfr, acc[i][0], 0, 0, 0);
                    acc[i][1] = __builtin_amdgcn_mfma_f32_16x16x32_bf16(a1, bfr, acc[i][1], 0, 0, 0);
                }
                a0 = na0; a1 = na1;
            }
            buf ^= 1;
        }
    }

    // ---- epilogue: D row r = sub*4+reg; co = (sub&1)*4+reg; variant = r>>3.
    // combine relu(A)+relu(B) across lane^32 pairs; lanes 0-31 store. ----
    const size_t spb = (size_t)(o1 * TS + o2) * TS2;
#pragma unroll
    for (int i = 0; i < 5; ++i) {
        const int p = (wave * 5 + i) * 16 + mrow;   // D column = spatial
#pragma unroll
        for (int mt = 0; mt < 2; ++mt) {
            const float* bs = mt ? b11 : b10;
            float* outc = y2 + ((size_t)n * 16 + mt * 8) * (TS2 * (size_t)TS2) + spb + p;
#pragma unroll
            for (int r = 0; r < 4; ++r) {
                const int co = (sub & 1) * 4 + r;
                float v = acc[i][mt][r] + bs[co];
                v = v > 0.0f ? v : 0.0f;
                const float o = v + __shfl_xor(v, 32);
                if (lane < 32) outc[(size_t)co * (TS2 * (size_t)TS2)] = o;
            }
        }
    }
}

// ---------------------------------------------------------------------------
extern "C" void kernel_launch(void* const* d_in, const int* in_sizes, int n_in,
                              void* d_out, int out_size, void* d_ws, size_t ws_size,
                              hipStream_t stream)
{
    const float* x   = (const float*)d_in[0];
    const float* w0  = (const float*)d_in[1];
    const float* b0  = (const float*)d_in[2];
    const float* w10 = (const float*)d_in[3];
    const float* b10 = (const float*)d_in[4];
    const float* w11 = (const float*)d_in[5];
    const float* b11 = (const float*)d_in[6];
    const float* w2  = (const float*)d_in[7];
    const float* b2  = (const float*)d_in[8];
    float* out = (float*)d_out;

    // workspace layout: y2 fp32 planar (40.96 MB) | y1 bf16 ilv (20.48 MB) | wpk
    float*  y2    = (float*)d_ws;
    __bf16* y1    = (__bf16*)((char*)d_ws + (size_t)4 * 16 * TS2 * TS2 * 4);
    __bf16* wpk   = y1 + (size_t)4 * TS2 * TS2 * 16;

    dim3 blk448(448), blk320(320), blk256(256);
    dim3 grid(4 * TS * TS);

    // pack fused weights for layers 10+11
    pack_weights<<<dim3((650 * 512 + 255) / 256), blk256, 0, stream>>>(w10, w11, wpk);

    // layer 0: fp32 direct conv, writes y1 interleaved bf16
    conv4d_sym<1, 16, 5, 5, 16, 0, true><<<grid, blk448, 0, stream>>>(x, w0, b0, (void*)y1);

    // layers 10+11 fused: MFMA implicit GEMM, writes y2 fp32 planar
    conv4d_mid_mfma<<<grid, blk320, 0, stream>>>(y1, wpk, b10, b11, y2);

    // layer 2: fp32 direct conv on y2
    conv4d_sym<16, 1, 5, 5, 1, 0, false><<<grid, blk448, 0, stream>>>(y2, w2, b2, (void*)out);
}

// Round 3
// 663.314 us; speedup vs baseline: 14.5658x; 2.8748x over previous
//
#include <hip/hip_runtime.h>

#define TS 20
#define TS2 400   // 20*20

typedef __attribute__((ext_vector_type(8))) __bf16 bf16x8;
typedef __attribute__((ext_vector_type(4))) __bf16 bf16x4;
typedef __attribute__((ext_vector_type(4))) float  f32x4;
typedef __attribute__((ext_vector_type(4))) int    int4v;

__device__ __forceinline__ float relu_f(float v) { return v > 0.0f ? v : 0.0f; }

// ---------------------------------------------------------------------------
// Weight packs.
// ---------------------------------------------------------------------------
// Layer 0: wpk0[e 25][m 32][c 32] bf16.  e = inner offset (d3,d4), row-major 5x5.
// c = outer offset (d1,d2) 0..24 (25..31 zero pad).  m: 0-15 A co, 16-31 B co.
__global__ __launch_bounds__(256)
void pack_w0(const float* __restrict__ w0, __bf16* __restrict__ wpk0)
{
    int idx = blockIdx.x * 256 + (int)threadIdx.x;
    if (idx >= 25 * 32 * 32) return;
    const int c = idx & 31;
    const int m = (idx >> 5) & 31;
    const int e = idx >> 10;
    float v = 0.0f;
    if (c < 25) {
        const int co = m & 15;
        const int k1o = c / 5, k2o = c % 5, k3i = e / 5, k4i = e % 5;
        if (m < 16) v = w0[co * 625 + k1o * 125 + k2o * 25 + k3i * 5 + k4i];
        else        v = w0[co * 625 + k3i * 125 + k4i * 25 + k1o * 5 + k2o];
    }
    wpk0[idx] = (__bf16)v;
}

// Mid (layers 10+11): wpk[off 650][m 32][ci 16]; off = outer*26 + inner (inner 25 = pad).
// m: 0-7 L10-A, 8-15 L10-B, 16-23 L11-A, 24-31 L11-B.
__global__ __launch_bounds__(256)
void pack_wmid(const float* __restrict__ w10, const float* __restrict__ w11,
               __bf16* __restrict__ wpk)
{
    int idx = blockIdx.x * 256 + (int)threadIdx.x;
    if (idx >= 650 * 512) return;
    const int ci  = idx & 15;
    const int m   = (idx >> 4) & 31;
    const int off = idx >> 9;
    const int inner = off % 26, outer = off / 26;
    const int d1 = outer / 5 - 2, d2 = outer % 5 - 2;
    float v = 0.0f;
    if (inner < 25) {
        const int d3 = inner / 5 - 2, d4 = inner % 5 - 2;
        const int co = m & 7;
        const bool isB  = (m & 8)  != 0;
        const bool is11 = (m & 16) != 0;
        if (is11) {
            int k1, k2, k3, k4;
            if (!isB) { k1 = d1 + 2; k2 = d2 + 2; k3 = d3 + 2; k4 = d4 + 2; }
            else      { k1 = d3 + 2; k2 = d4 + 2; k3 = d1 + 2; k4 = d2 + 2; }
            v = w11[((((co * 16 + ci) * 5 + k1) * 5 + k2) * 5 + k3) * 5 + k4];
        } else {
            if (!isB) {
                if (d1 >= -1 && d1 <= 1 && d2 >= -1 && d2 <= 1)
                    v = w10[((((co * 16 + ci) * 3 + (d1 + 1)) * 3 + (d2 + 1)) * 5 + (d3 + 2)) * 5 + (d4 + 2)];
            } else {
                if (d3 >= -1 && d3 <= 1 && d4 >= -1 && d4 <= 1)
                    v = w10[((((co * 16 + ci) * 3 + (d3 + 1)) * 3 + (d4 + 1)) * 5 + (d1 + 2)) * 5 + (d2 + 2)];
            }
        }
    }
    wpk[idx] = (__bf16)v;
}

// Layer 2: wpk2[off 650][m 16][ci 16]; m0 = A co0, m1 = B co0, rest zero.
__global__ __launch_bounds__(256)
void pack_w2(const float* __restrict__ w2, __bf16* __restrict__ wpk2)
{
    int idx = blockIdx.x * 256 + (int)threadIdx.x;
    if (idx >= 650 * 256) return;
    const int ci = idx & 15;
    const int m  = (idx >> 4) & 15;
    const int off = idx >> 8;
    const int inner = off % 26, outer = off / 26;
    float v = 0.0f;
    if (inner < 25 && m < 2) {
        if (m == 0) v = w2[ci * 625 + (outer / 5) * 125 + (outer % 5) * 25 + (inner / 5) * 5 + inner % 5];
        else        v = w2[ci * 625 + (inner / 5) * 125 + (inner % 5) * 25 + (outer / 5) * 5 + outer % 5];
    }
    wpk2[idx] = (__bf16)v;
}

// ---------------------------------------------------------------------------
// Layer 0 MFMA: CIN=1.  Virtual channels = 25 outer offsets (pad 32); K-chunks
// = 25 inner offsets.  All planes staged once -> barrier-free compute.
// LDS V[r 24][cl 24][c 40] bf16 (stride 40: 2-way bank aliasing only).
// y1 out: bf16 interleaved [n][o1][o2][p][ci16].
// ---------------------------------------------------------------------------
__global__ __launch_bounds__(320)
void conv0_mfma(const float* __restrict__ x, const __bf16* __restrict__ wpk0,
                const float* __restrict__ b0, __bf16* __restrict__ y1)
{
    __shared__ __bf16 lds0[576 * 40];   // 46.08 KB

    const int tid  = (int)threadIdx.x;
    const int lane = tid & 63;
    const int wave = tid >> 6;
    const int bid  = blockIdx.x;
    const int o2 = bid % TS, o1 = (bid / TS) % TS, n = bid / TS2;

    for (int i = tid; i < 576 * 40 / 2; i += 320) ((int*)lds0)[i] = 0;
    __syncthreads();

    // stage 25 planes, channel-innermost
    for (int c = tid; c < 25 * TS2; c += 320) {
        const int pl = c / TS2, pt = c % TS2;
        const int i1 = o1 + pl / 5 - 2, i2 = o2 + pl % 5 - 2;
        if (i1 >= 0 && i1 < TS && i2 >= 0 && i2 < TS) {
            const float v = x[(size_t)((n * TS + i1) * TS + i2) * TS2 + pt];
            const int h = pt / TS, w = pt % TS;
            lds0[((h + 2) * 24 + (w + 2)) * 40 + pl] = (__bf16)v;
        }
    }
    __syncthreads();

    const int mrow = lane & 15;
    const int sub  = lane >> 4;

    int sb[5];
#pragma unroll
    for (int i = 0; i < 5; ++i) {
        const int p = (wave * 5 + i) * 16 + mrow;
        sb[i] = ((p / TS + 2) * 24 + (p % TS + 2)) * 40 + sub * 8;
    }

    f32x4 acc0[5], acc1[5];
#pragma unroll
    for (int i = 0; i < 5; ++i) {
        acc0[i] = (f32x4){0.f, 0.f, 0.f, 0.f};
        acc1[i] = (f32x4){0.f, 0.f, 0.f, 0.f};
    }

    bf16x8 a0 = *(const bf16x8*)(wpk0 + ((size_t)(0 * 32 + mrow)) * 32 + sub * 8);
    bf16x8 a1 = *(const bf16x8*)(wpk0 + ((size_t)(0 * 32 + 16 + mrow)) * 32 + sub * 8);
    for (int e = 0; e < 25; ++e) {
        bf16x8 na0 = a0, na1 = a1;
        if (e < 24) {
            na0 = *(const bf16x8*)(wpk0 + ((size_t)((e + 1) * 32 + mrow)) * 32 + sub * 8);
            na1 = *(const bf16x8*)(wpk0 + ((size_t)((e + 1) * 32 + 16 + mrow)) * 32 + sub * 8);
        }
        const int delta = ((e / 5 - 2) * 24 + (e % 5 - 2)) * 40;
#pragma unroll
        for (int i = 0; i < 5; ++i) {
            bf16x8 bfr = *(const bf16x8*)(&lds0[sb[i] + delta]);
            acc0[i] = __builtin_amdgcn_mfma_f32_16x16x32_bf16(a0, bfr, acc0[i], 0, 0, 0);
            acc1[i] = __builtin_amdgcn_mfma_f32_16x16x32_bf16(a1, bfr, acc1[i], 0, 0, 0);
        }
        a0 = na0; a1 = na1;
    }

    // epilogue: D row = sub*4+reg = co; col = mrow = spatial. A/B combined in-lane.
    const f32x4 bv = *(const f32x4*)(b0 + sub * 4);
#pragma unroll
    for (int i = 0; i < 5; ++i) {
        const int p = (wave * 5 + i) * 16 + mrow;
        bf16x4 pk;
#pragma unroll
        for (int r = 0; r < 4; ++r)
            pk[r] = (__bf16)(relu_f(acc0[i][r] + bv[r]) + relu_f(acc1[i][r] + bv[r]));
        *(bf16x4*)(y1 + ((size_t)bid * TS2 + p) * 16 + sub * 4) = pk;
    }
}

// ---------------------------------------------------------------------------
// Fused layers 10+11 MFMA (as round 2), epilogue now writes interleaved bf16.
// ---------------------------------------------------------------------------
__global__ __launch_bounds__(320)
void conv4d_mid_mfma(const __bf16* __restrict__ y1, const __bf16* __restrict__ wpk,
                     const float* __restrict__ b10, const float* __restrict__ b11,
                     __bf16* __restrict__ y2)
{
    __shared__ __bf16 lds[2][9216];   // [24][24][16ci] x2

    const int tid  = (int)threadIdx.x;
    const int lane = tid & 63;
    const int wave = tid >> 6;
    const int bid = blockIdx.x;
    const int o2 = bid % TS, o1 = (bid / TS) % TS, n = bid / TS2;

    for (int i = tid; i < 9216; i += 320) ((int*)lds)[i] = 0;

    const int mrow = lane & 15;
    const int sub  = lane >> 4;
    const int ci0  = (sub & 1) * 8;
    const int aoff = (sub >> 1) * 512 + mrow * 16 + ci0;

    int sbase[5];
#pragma unroll
    for (int i = 0; i < 5; ++i) {
        const int p  = (wave * 5 + i) * 16 + mrow;
        sbase[i] = ((p / TS + 2) * 24 + (p % TS + 2)) * 16 + ci0;
    }

    f32x4 acc[5][2];
#pragma unroll
    for (int i = 0; i < 5; ++i) {
        acc[i][0] = (f32x4){0.f, 0.f, 0.f, 0.f};
        acc[i][1] = (f32x4){0.f, 0.f, 0.f, 0.f};
    }

    __syncthreads();

    int buf = 0;
    for (int d1 = -2; d1 <= 2; ++d1) {
        const int i1 = o1 + d1;
        if (i1 < 0 || i1 >= TS) continue;
        for (int d2 = -2; d2 <= 2; ++d2) {
            const int i2 = o2 + d2;
            if (i2 < 0 || i2 >= TS) continue;

            const __bf16* src = y1 + (size_t)((n * TS + i1) * TS + i2) * TS2 * 16;
            for (int c = tid; c < 800; c += 320) {
                const int h = c / 40, rem = c % 40;
                int4v v = *(const int4v*)(src + c * 8);
                *(int4v*)(&lds[buf][((h + 2) * 24 + 2) * 16 + rem * 8]) = v;
            }
            __syncthreads();

            const int outer = (d1 + 2) * 5 + (d2 + 2);
            const __bf16* wbase = wpk + (size_t)outer * 26 * 512;

            bf16x8 a0 = *(const bf16x8*)(wbase + aoff);
            bf16x8 a1 = *(const bf16x8*)(wbase + aoff + 256);
            for (int ic = 0; ic < 13; ++ic) {
                bf16x8 na0 = a0, na1 = a1;
                if (ic < 12) {
                    na0 = *(const bf16x8*)(wbase + (ic + 1) * 1024 + aoff);
                    na1 = *(const bf16x8*)(wbase + (ic + 1) * 1024 + aoff + 256);
                }
                const int e = 2 * ic + (sub >> 1);
                int d3 = 0, d4 = 0;
                if (e < 25) { d3 = e / 5 - 2; d4 = e % 5 - 2; }
                const int delta = (d3 * 24 + d4) * 16;
#pragma unroll
                for (int i = 0; i < 5; ++i) {
                    bf16x8 bfr = *(const bf16x8*)(&lds[buf][sbase[i] + delta]);
                    acc[i][0] = __builtin_amdgcn_mfma_f32_16x16x32_bf16(a0, bfr, acc[i][0], 0, 0, 0);
                    acc[i][1] = __builtin_amdgcn_mfma_f32_16x16x32_bf16(a1, bfr, acc[i][1], 0, 0, 0);
                }
                a0 = na0; a1 = na1;
            }
            buf ^= 1;
        }
    }

    // epilogue -> interleaved bf16 [p][ch], ch = mt*8 + (sub&1)*4 + r
    const size_t base = (size_t)bid * TS2 * 16;
#pragma unroll
    for (int i = 0; i < 5; ++i) {
        const int p = (wave * 5 + i) * 16 + mrow;
#pragma unroll
        for (int mt = 0; mt < 2; ++mt) {
            const float* bs = mt ? b11 : b10;
            const f32x4 bv = *(const f32x4*)(bs + (sub & 1) * 4);
            bf16x4 pk;
#pragma unroll
            for (int r = 0; r < 4; ++r) {
                float v = relu_f(acc[i][mt][r] + bv[r]);
                float o = v + __shfl_xor(v, 32);
                pk[r] = (__bf16)o;
            }
            if (lane < 32)
                *(bf16x4*)(y2 + base + (size_t)p * 16 + mt * 8 + (sub & 1) * 4) = pk;
        }
    }
}

// ---------------------------------------------------------------------------
// Layer 2 MFMA: COUT=1; single M-tile, rows 0/1 = A/B variant.
// ---------------------------------------------------------------------------
__global__ __launch_bounds__(320)
void conv2_mfma(const __bf16* __restrict__ y2, const __bf16* __restrict__ wpk2,
                const float* __restrict__ b2, float* __restrict__ out)
{
    __shared__ __bf16 lds[2][9216];

    const int tid  = (int)threadIdx.x;
    const int lane = tid & 63;
    const int wave = tid >> 6;
    const int bid = blockIdx.x;
    const int o2 = bid % TS, o1 = (bid / TS) % TS, n = bid / TS2;

    for (int i = tid; i < 9216; i += 320) ((int*)lds)[i] = 0;

    const int mrow = lane & 15;
    const int sub  = lane >> 4;
    const int ci0  = (sub & 1) * 8;
    const int aoff = (sub >> 1) * 256 + mrow * 16 + ci0;

    int sbase[5];
#pragma unroll
    for (int i = 0; i < 5; ++i) {
        const int p  = (wave * 5 + i) * 16 + mrow;
        sbase[i] = ((p / TS + 2) * 24 + (p % TS + 2)) * 16 + ci0;
    }

    f32x4 acc[5];
#pragma unroll
    for (int i = 0; i < 5; ++i) acc[i] = (f32x4){0.f, 0.f, 0.f, 0.f};

    __syncthreads();

    int buf = 0;
    for (int d1 = -2; d1 <= 2; ++d1) {
        const int i1 = o1 + d1;
        if (i1 < 0 || i1 >= TS) continue;
        for (int d2 = -2; d2 <= 2; ++d2) {
            const int i2 = o2 + d2;
            if (i2 < 0 || i2 >= TS) continue;

            const __bf16* src = y2 + (size_t)((n * TS + i1) * TS + i2) * TS2 * 16;
            for (int c = tid; c < 800; c += 320) {
                const int h = c / 40, rem = c % 40;
                int4v v = *(const int4v*)(src + c * 8);
                *(int4v*)(&lds[buf][((h + 2) * 24 + 2) * 16 + rem * 8]) = v;
            }
            __syncthreads();

            const int outer = (d1 + 2) * 5 + (d2 + 2);
            const __bf16* wbase = wpk2 + (size_t)outer * 26 * 256;

            bf16x8 a = *(const bf16x8*)(wbase + aoff);
            for (int ic = 0; ic < 13; ++ic) {
                bf16x8 na = a;
                if (ic < 12) na = *(const bf16x8*)(wbase + (ic + 1) * 512 + aoff);
                const int e = 2 * ic + (sub >> 1);
                int d3 = 0, d4 = 0;
                if (e < 25) { d3 = e / 5 - 2; d4 = e % 5 - 2; }
                const int delta = (d3 * 24 + d4) * 16;
#pragma unroll
                for (int i = 0; i < 5; ++i) {
                    bf16x8 bfr = *(const bf16x8*)(&lds[buf][sbase[i] + delta]);
                    acc[i] = __builtin_amdgcn_mfma_f32_16x16x32_bf16(a, bfr, acc[i], 0, 0, 0);
                }
                a = na;
            }
            buf ^= 1;
        }
    }

    // rows 0 (A) and 1 (B) live in sub==0 lanes, regs 0/1
    if (sub == 0) {
        const float bias = b2[0];
#pragma unroll
        for (int i = 0; i < 5; ++i) {
            const int p = (wave * 5 + i) * 16 + mrow;
            out[(size_t)bid * TS2 + p] = relu_f(acc[i][0] + bias) + relu_f(acc[i][1] + bias);
        }
    }
}

// ---------------------------------------------------------------------------
extern "C" void kernel_launch(void* const* d_in, const int* in_sizes, int n_in,
                              void* d_out, int out_size, void* d_ws, size_t ws_size,
                              hipStream_t stream)
{
    const float* x   = (const float*)d_in[0];
    const float* w0  = (const float*)d_in[1];
    const float* b0  = (const float*)d_in[2];
    const float* w10 = (const float*)d_in[3];
    const float* b10 = (const float*)d_in[4];
    const float* w11 = (const float*)d_in[5];
    const float* b11 = (const float*)d_in[6];
    const float* w2  = (const float*)d_in[7];
    const float* b2  = (const float*)d_in[8];
    float* out = (float*)d_out;

    // workspace: y1 bf16 (20.48 MB) | y2 bf16 (20.48 MB) | wpk_mid | wpk0 | wpk2
    __bf16* y1   = (__bf16*)d_ws;
    __bf16* y2   = y1 + (size_t)4 * TS2 * TS2 * 16;
    __bf16* wpkm = y2 + (size_t)4 * TS2 * TS2 * 16;
    __bf16* wpk0 = wpkm + 650 * 512;
    __bf16* wpk2 = wpk0 + 25 * 32 * 32;

    dim3 blk320(320), blk256(256);
    dim3 grid(4 * TS * TS);

    pack_w0  <<<dim3((25 * 1024 + 255) / 256), blk256, 0, stream>>>(w0, wpk0);
    pack_wmid<<<dim3((650 * 512 + 255) / 256), blk256, 0, stream>>>(w10, w11, wpkm);
    pack_w2  <<<dim3((650 * 256 + 255) / 256), blk256, 0, stream>>>(w2, wpk2);

    conv0_mfma     <<<grid, blk320, 0, stream>>>(x, wpk0, b0, y1);
    conv4d_mid_mfma<<<grid, blk320, 0, stream>>>(y1, wpkm, b10, b11, y2);
    conv2_mfma     <<<grid, blk320, 0, stream>>>(y2, wpk2, b2, out);
}

// Round 4
// 642.443 us; speedup vs baseline: 15.0390x; 1.0325x over previous
//
#include <hip/hip_runtime.h>

#define TS 20
#define TS2 400   // 20*20

typedef __attribute__((ext_vector_type(8))) __bf16 bf16x8;
typedef __attribute__((ext_vector_type(4))) __bf16 bf16x4;
typedef __attribute__((ext_vector_type(4))) float  f32x4;
typedef __attribute__((ext_vector_type(4))) int    int4v;

__device__ __forceinline__ float relu_f(float v) { return v > 0.0f ? v : 0.0f; }
// LDS anti-bank-conflict swizzle on bf16 element index: XOR 16B-slot bits 0-2
// with bits 3-5 (involution; permutes within 512-element blocks).
__device__ __forceinline__ int swz(int idx) { return idx ^ (((idx >> 6) & 7) << 3); }

// ---------------------------------------------------------------------------
// Weight packs.
// ---------------------------------------------------------------------------
// Layer 0: wpk0[e 25][m 32][c 32]; c = outer offset (25 real), m: 0-15 A, 16-31 B.
__global__ __launch_bounds__(256)
void pack_w0(const float* __restrict__ w0, __bf16* __restrict__ wpk0)
{
    int idx = blockIdx.x * 256 + (int)threadIdx.x;
    if (idx >= 25 * 32 * 32) return;
    const int c = idx & 31;
    const int m = (idx >> 5) & 31;
    const int e = idx >> 10;
    float v = 0.0f;
    if (c < 25) {
        const int co = m & 15;
        const int k1o = c / 5, k2o = c % 5, k3i = e / 5, k4i = e % 5;
        if (m < 16) v = w0[co * 625 + k1o * 125 + k2o * 25 + k3i * 5 + k4i];
        else        v = w0[co * 625 + k3i * 125 + k4i * 25 + k1o * 5 + k2o];
    }
    wpk0[idx] = (__bf16)v;
}

// Mid: wpk[off 650][m 32][ci 16]; off = outer*26 + inner (25 = pad).
__global__ __launch_bounds__(256)
void pack_wmid(const float* __restrict__ w10, const float* __restrict__ w11,
               __bf16* __restrict__ wpk)
{
    int idx = blockIdx.x * 256 + (int)threadIdx.x;
    if (idx >= 650 * 512) return;
    const int ci  = idx & 15;
    const int m   = (idx >> 4) & 31;
    const int off = idx >> 9;
    const int inner = off % 26, outer = off / 26;
    const int d1 = outer / 5 - 2, d2 = outer % 5 - 2;
    float v = 0.0f;
    if (inner < 25) {
        const int d3 = inner / 5 - 2, d4 = inner % 5 - 2;
        const int co = m & 7;
        const bool isB  = (m & 8)  != 0;
        const bool is11 = (m & 16) != 0;
        if (is11) {
            int k1, k2, k3, k4;
            if (!isB) { k1 = d1 + 2; k2 = d2 + 2; k3 = d3 + 2; k4 = d4 + 2; }
            else      { k1 = d3 + 2; k2 = d4 + 2; k3 = d1 + 2; k4 = d2 + 2; }
            v = w11[((((co * 16 + ci) * 5 + k1) * 5 + k2) * 5 + k3) * 5 + k4];
        } else {
            if (!isB) {
                if (d1 >= -1 && d1 <= 1 && d2 >= -1 && d2 <= 1)
                    v = w10[((((co * 16 + ci) * 3 + (d1 + 1)) * 3 + (d2 + 1)) * 5 + (d3 + 2)) * 5 + (d4 + 2)];
            } else {
                if (d3 >= -1 && d3 <= 1 && d4 >= -1 && d4 <= 1)
                    v = w10[((((co * 16 + ci) * 3 + (d3 + 1)) * 3 + (d4 + 1)) * 5 + (d1 + 2)) * 5 + (d2 + 2)];
            }
        }
    }
    wpk[idx] = (__bf16)v;
}

// Layer 2 factorized: wpk2f[e 26][m 64][ci 16].
// m 0-24: A rows (do=m), m 32-56: B rows (do=m-32), else 0; e=25 is K pad.
__global__ __launch_bounds__(256)
void pack_w2f(const float* __restrict__ w2, __bf16* __restrict__ wpk2f)
{
    int idx = blockIdx.x * 256 + (int)threadIdx.x;
    if (idx >= 26 * 64 * 16) return;
    const int ci = idx & 15;
    const int m  = (idx >> 4) & 63;
    const int e  = idx >> 10;
    float v = 0.0f;
    if (e < 25) {
        if (m < 25)
            v = w2[ci * 625 + (m / 5) * 125 + (m % 5) * 25 + (e / 5) * 5 + (e % 5)];
        else if (m >= 32 && m < 57) {
            const int dd = m - 32;
            v = w2[ci * 625 + (e / 5) * 125 + (e % 5) * 25 + (dd / 5) * 5 + (dd % 5)];
        }
    }
    wpk2f[idx] = (__bf16)v;
}

// ---------------------------------------------------------------------------
// Layer 0 MFMA (unchanged): virtual channels = 25 outer offsets.
// ---------------------------------------------------------------------------
__global__ __launch_bounds__(320)
void conv0_mfma(const float* __restrict__ x, const __bf16* __restrict__ wpk0,
                const float* __restrict__ b0, __bf16* __restrict__ y1)
{
    __shared__ __bf16 lds0[576 * 40];

    const int tid  = (int)threadIdx.x;
    const int lane = tid & 63;
    const int wave = tid >> 6;
    const int bid  = blockIdx.x;
    const int o2 = bid % TS, o1 = (bid / TS) % TS, n = bid / TS2;

    for (int i = tid; i < 576 * 40 / 2; i += 320) ((int*)lds0)[i] = 0;
    __syncthreads();

    for (int c = tid; c < 25 * TS2; c += 320) {
        const int pl = c / TS2, pt = c % TS2;
        const int i1 = o1 + pl / 5 - 2, i2 = o2 + pl % 5 - 2;
        if (i1 >= 0 && i1 < TS && i2 >= 0 && i2 < TS) {
            const float v = x[(size_t)((n * TS + i1) * TS + i2) * TS2 + pt];
            lds0[((pt / TS + 2) * 24 + (pt % TS + 2)) * 40 + pl] = (__bf16)v;
        }
    }
    __syncthreads();

    const int mrow = lane & 15;
    const int sub  = lane >> 4;

    int sb[5];
#pragma unroll
    for (int i = 0; i < 5; ++i) {
        const int p = (wave * 5 + i) * 16 + mrow;
        sb[i] = ((p / TS + 2) * 24 + (p % TS + 2)) * 40 + sub * 8;
    }

    f32x4 acc0[5], acc1[5];
#pragma unroll
    for (int i = 0; i < 5; ++i) {
        acc0[i] = (f32x4){0.f, 0.f, 0.f, 0.f};
        acc1[i] = (f32x4){0.f, 0.f, 0.f, 0.f};
    }

    bf16x8 a0 = *(const bf16x8*)(wpk0 + (size_t)mrow * 32 + sub * 8);
    bf16x8 a1 = *(const bf16x8*)(wpk0 + (size_t)(16 + mrow) * 32 + sub * 8);
    for (int e = 0; e < 25; ++e) {
        bf16x8 na0 = a0, na1 = a1;
        if (e < 24) {
            na0 = *(const bf16x8*)(wpk0 + ((size_t)((e + 1) * 32 + mrow)) * 32 + sub * 8);
            na1 = *(const bf16x8*)(wpk0 + ((size_t)((e + 1) * 32 + 16 + mrow)) * 32 + sub * 8);
        }
        const int delta = ((e / 5 - 2) * 24 + (e % 5 - 2)) * 40;
#pragma unroll
        for (int i = 0; i < 5; ++i) {
            bf16x8 bfr = *(const bf16x8*)(&lds0[sb[i] + delta]);
            acc0[i] = __builtin_amdgcn_mfma_f32_16x16x32_bf16(a0, bfr, acc0[i], 0, 0, 0);
            acc1[i] = __builtin_amdgcn_mfma_f32_16x16x32_bf16(a1, bfr, acc1[i], 0, 0, 0);
        }
        a0 = na0; a1 = na1;
    }

    const f32x4 bv = *(const f32x4*)(b0 + sub * 4);
#pragma unroll
    for (int i = 0; i < 5; ++i) {
        const int p = (wave * 5 + i) * 16 + mrow;
        bf16x4 pk;
#pragma unroll
        for (int r = 0; r < 4; ++r)
            pk[r] = (__bf16)(relu_f(acc0[i][r] + bv[r]) + relu_f(acc1[i][r] + bv[r]));
        *(bf16x4*)(y1 + ((size_t)bid * TS2 + p) * 16 + sub * 4) = pk;
    }
}

// ---------------------------------------------------------------------------
// Fused layers 10+11 MFMA, + LDS swizzle + XCD-aware bid remap.
// ---------------------------------------------------------------------------
__global__ __launch_bounds__(320)
void conv4d_mid_mfma(const __bf16* __restrict__ y1, const __bf16* __restrict__ wpk,
                     const float* __restrict__ b10, const float* __restrict__ b11,
                     __bf16* __restrict__ y2)
{
    __shared__ __bf16 lds[2][9216];

    const int tid  = (int)threadIdx.x;
    const int lane = tid & 63;
    const int wave = tid >> 6;
    // XCD swizzle: 1600 blocks = 8 XCDs x 200 contiguous tiles (bijective)
    const int bid0 = blockIdx.x;
    const int bid  = (bid0 & 7) * 200 + (bid0 >> 3);
    const int o2 = bid % TS, o1 = (bid / TS) % TS, n = bid / TS2;

    for (int i = tid; i < 9216; i += 320) ((int*)lds)[i] = 0;

    const int mrow = lane & 15;
    const int sub  = lane >> 4;
    const int ci0  = (sub & 1) * 8;
    const int aoff = (sub >> 1) * 512 + mrow * 16 + ci0;

    int sbase[5];
#pragma unroll
    for (int i = 0; i < 5; ++i) {
        const int p  = (wave * 5 + i) * 16 + mrow;
        sbase[i] = ((p / TS + 2) * 24 + (p % TS + 2)) * 16 + ci0;
    }

    f32x4 acc[5][2];
#pragma unroll
    for (int i = 0; i < 5; ++i) {
        acc[i][0] = (f32x4){0.f, 0.f, 0.f, 0.f};
        acc[i][1] = (f32x4){0.f, 0.f, 0.f, 0.f};
    }

    __syncthreads();

    int buf = 0;
    for (int d1 = -2; d1 <= 2; ++d1) {
        const int i1 = o1 + d1;
        if (i1 < 0 || i1 >= TS) continue;
        for (int d2 = -2; d2 <= 2; ++d2) {
            const int i2 = o2 + d2;
            if (i2 < 0 || i2 >= TS) continue;

            const __bf16* src = y1 + (size_t)((n * TS + i1) * TS + i2) * TS2 * 16;
            for (int c = tid; c < 800; c += 320) {
                const int h = c / 40, rem = c % 40;
                int4v v = *(const int4v*)(src + c * 8);
                *(int4v*)(&lds[buf][swz(((h + 2) * 24 + 2) * 16 + rem * 8)]) = v;
            }
            __syncthreads();

            const int outer = (d1 + 2) * 5 + (d2 + 2);
            const __bf16* wbase = wpk + (size_t)outer * 26 * 512;

            bf16x8 a0 = *(const bf16x8*)(wbase + aoff);
            bf16x8 a1 = *(const bf16x8*)(wbase + aoff + 256);
            for (int ic = 0; ic < 13; ++ic) {
                bf16x8 na0 = a0, na1 = a1;
                if (ic < 12) {
                    na0 = *(const bf16x8*)(wbase + (ic + 1) * 1024 + aoff);
                    na1 = *(const bf16x8*)(wbase + (ic + 1) * 1024 + aoff + 256);
                }
                const int e = 2 * ic + (sub >> 1);
                int d3 = 0, d4 = 0;
                if (e < 25) { d3 = e / 5 - 2; d4 = e % 5 - 2; }
                const int delta = (d3 * 24 + d4) * 16;
#pragma unroll
                for (int i = 0; i < 5; ++i) {
                    bf16x8 bfr = *(const bf16x8*)(&lds[buf][swz(sbase[i] + delta)]);
                    acc[i][0] = __builtin_amdgcn_mfma_f32_16x16x32_bf16(a0, bfr, acc[i][0], 0, 0, 0);
                    acc[i][1] = __builtin_amdgcn_mfma_f32_16x16x32_bf16(a1, bfr, acc[i][1], 0, 0, 0);
                }
                a0 = na0; a1 = na1;
            }
            buf ^= 1;
        }
    }

    const size_t base = (size_t)bid * TS2 * 16;
#pragma unroll
    for (int i = 0; i < 5; ++i) {
        const int p = (wave * 5 + i) * 16 + mrow;
#pragma unroll
        for (int mt = 0; mt < 2; ++mt) {
            const float* bs = mt ? b11 : b10;
            const f32x4 bv = *(const f32x4*)(bs + (sub & 1) * 4);
            bf16x4 pk;
#pragma unroll
            for (int r = 0; r < 4; ++r) {
                float v = relu_f(acc[i][mt][r] + bv[r]);
                float o = v + __shfl_xor(v, 32);
                pk[r] = (__bf16)o;
            }
            if (lane < 32)
                *(bf16x4*)(y2 + base + (size_t)p * 16 + mt * 8 + (sub & 1) * 4) = pk;
        }
    }
}

// ---------------------------------------------------------------------------
// Layer 2 pass 1: t[q, m] = sum_{di,ci} wpk2f[di][m][ci] * y2[q, .+di, ci].
// M = 64 rows (50 real: 25 A-do + 25 B-do), K = 26x16, one staging per block.
// t layout: [nl][q1][q2][m 50][p 400] bf16.
// ---------------------------------------------------------------------------
__global__ __launch_bounds__(320)
void conv2t_mfma(const __bf16* __restrict__ y2, const __bf16* __restrict__ wpk2f,
                 int n0, __bf16* __restrict__ t)
{
    __shared__ __bf16 lds[9216];

    const int tid  = (int)threadIdx.x;
    const int lane = tid & 63;
    const int wave = tid >> 6;
    const int bid = blockIdx.x;
    const int q2 = bid % TS, q1 = (bid / TS) % TS, nl = bid / TS2;

    for (int i = tid; i < 4608; i += 320) ((int*)lds)[i] = 0;
    __syncthreads();

    const __bf16* src = y2 + (size_t)(((n0 + nl) * TS + q1) * TS + q2) * TS2 * 16;
    for (int c = tid; c < 800; c += 320) {
        const int h = c / 40, rem = c % 40;
        int4v v = *(const int4v*)(src + c * 8);
        *(int4v*)(&lds[swz(((h + 2) * 24 + 2) * 16 + rem * 8)]) = v;
    }
    __syncthreads();

    const int mrow = lane & 15;
    const int sub  = lane >> 4;
    const int ci0  = (sub & 1) * 8;

    int sbase[5];
#pragma unroll
    for (int i = 0; i < 5; ++i) {
        const int p  = (wave * 5 + i) * 16 + mrow;
        sbase[i] = ((p / TS + 2) * 24 + (p % TS + 2)) * 16 + ci0;
    }

    f32x4 acc[5][4];
#pragma unroll
    for (int i = 0; i < 5; ++i)
#pragma unroll
        for (int mt = 0; mt < 4; ++mt)
            acc[i][mt] = (f32x4){0.f, 0.f, 0.f, 0.f};

    for (int ic = 0; ic < 13; ++ic) {
        const int e = 2 * ic + (sub >> 1);
        int d3 = 0, d4 = 0;
        if (e < 25) { d3 = e / 5 - 2; d4 = e % 5 - 2; }
        const int delta = (d3 * 24 + d4) * 16;
        const __bf16* abase = wpk2f + ((size_t)e * 64 + mrow) * 16 + ci0;
        bf16x8 a0 = *(const bf16x8*)(abase);
        bf16x8 a1 = *(const bf16x8*)(abase + 256);
        bf16x8 a2 = *(const bf16x8*)(abase + 512);
        bf16x8 a3 = *(const bf16x8*)(abase + 768);
#pragma unroll
        for (int i = 0; i < 5; ++i) {
            bf16x8 bfr = *(const bf16x8*)(&lds[swz(sbase[i] + delta)]);
            acc[i][0] = __builtin_amdgcn_mfma_f32_16x16x32_bf16(a0, bfr, acc[i][0], 0, 0, 0);
            acc[i][1] = __builtin_amdgcn_mfma_f32_16x16x32_bf16(a1, bfr, acc[i][1], 0, 0, 0);
            acc[i][2] = __builtin_amdgcn_mfma_f32_16x16x32_bf16(a2, bfr, acc[i][2], 0, 0, 0);
            acc[i][3] = __builtin_amdgcn_mfma_f32_16x16x32_bf16(a3, bfr, acc[i][3], 0, 0, 0);
        }
    }

    // D row = sub*4 + r within tile; global m = mt*16 + sub*4 + r.
    // t m50: A rows 0-24 -> m50=gm; B rows 32-56 -> m50=gm-7.
    __bf16* tb = t + (size_t)((nl * TS + q1) * TS + q2) * (50 * TS2);
#pragma unroll
    for (int i = 0; i < 5; ++i) {
        const int p = (wave * 5 + i) * 16 + mrow;
#pragma unroll
        for (int mt = 0; mt < 4; ++mt) {
#pragma unroll
            for (int r = 0; r < 4; ++r) {
                const int gm = mt * 16 + sub * 4 + r;
                int m50 = -1;
                if (gm < 25) m50 = gm;
                else if (gm >= 32 && gm < 57) m50 = gm - 7;
                if (m50 >= 0) tb[m50 * TS2 + p] = (__bf16)acc[i][mt][r];
            }
        }
    }
}

// ---------------------------------------------------------------------------
// Layer 2 pass 2: out[o] = relu(b + sum_do tA[o+do-2, do]) + relu(b + ... tB).
// ---------------------------------------------------------------------------
__global__ __launch_bounds__(448)
void conv2_sum(const __bf16* __restrict__ t, const float* __restrict__ b2,
               int n0, float* __restrict__ out)
{
    const int tid = (int)threadIdx.x;
    if (tid >= TS2) return;
    const int bid = blockIdx.x;
    const int o2 = bid % TS, o1 = (bid / TS) % TS, nl = bid / TS2;

    float accA = 0.0f, accB = 0.0f;
    for (int dd = 0; dd < 25; ++dd) {
        const int q1 = o1 + dd / 5 - 2, q2 = o2 + dd % 5 - 2;
        if (q1 < 0 || q1 >= TS || q2 < 0 || q2 >= TS) continue;
        const __bf16* tb = t + (size_t)((nl * TS + q1) * TS + q2) * (50 * TS2) + tid;
        accA += (float)tb[dd * TS2];
        accB += (float)tb[(25 + dd) * TS2];
    }
    const float bias = b2[0];
    out[(size_t)(n0 + nl) * (TS2 * (size_t)TS2) + (size_t)(o1 * TS + o2) * TS2 + tid] =
        relu_f(accA + bias) + relu_f(accB + bias);
}

// ---------------------------------------------------------------------------
extern "C" void kernel_launch(void* const* d_in, const int* in_sizes, int n_in,
                              void* d_out, int out_size, void* d_ws, size_t ws_size,
                              hipStream_t stream)
{
    const float* x   = (const float*)d_in[0];
    const float* w0  = (const float*)d_in[1];
    const float* b0  = (const float*)d_in[2];
    const float* w10 = (const float*)d_in[3];
    const float* b10 = (const float*)d_in[4];
    const float* w11 = (const float*)d_in[5];
    const float* b11 = (const float*)d_in[6];
    const float* w2  = (const float*)d_in[7];
    const float* b2  = (const float*)d_in[8];
    float* out = (float*)d_out;

    // ws: y1 20.5MB | y2 20.5MB | t 32MB (2-image chunk) | packs ~0.8MB = ~74MB
    __bf16* y1    = (__bf16*)d_ws;
    __bf16* y2    = y1 + (size_t)10240000;
    __bf16* tbuf  = y2 + (size_t)10240000;
    __bf16* wpkm  = tbuf + (size_t)16000000;
    __bf16* wpk0  = wpkm + 650 * 512;
    __bf16* wpk2f = wpk0 + 25 * 32 * 32;

    dim3 blk320(320), blk256(256), blk448(448);
    dim3 grid(4 * TS * TS);

    pack_w0  <<<dim3((25600 + 255) / 256),  blk256, 0, stream>>>(w0, wpk0);
    pack_wmid<<<dim3((332800 + 255) / 256), blk256, 0, stream>>>(w10, w11, wpkm);
    pack_w2f <<<dim3((26624 + 255) / 256),  blk256, 0, stream>>>(w2, wpk2f);

    conv0_mfma     <<<grid, blk320, 0, stream>>>(x, wpk0, b0, y1);
    conv4d_mid_mfma<<<grid, blk320, 0, stream>>>(y1, wpkm, b10, b11, y2);

    for (int n0 = 0; n0 < 4; n0 += 2) {
        conv2t_mfma<<<dim3(800), blk320, 0, stream>>>(y2, wpk2f, n0, tbuf);
        conv2_sum  <<<dim3(800), blk448, 0, stream>>>(tbuf, b2, n0, out);
    }
}